// Round 7
// baseline (289.549 us; speedup 1.0000x reference)
//
#include <hip/hip_runtime.h>
#include <hip/hip_bf16.h>

#define IN_F 4096
#define OUT_F 4096
#define M_ROWS 8192

#define BM 256
#define BN 256
#define BK 64
#define NT 64                  // IN_F / BK K-tiles

typedef __attribute__((ext_vector_type(8))) __bf16 bf16x8;
typedef __attribute__((ext_vector_type(16))) float f32x16;
typedef __attribute__((address_space(1))) const unsigned int GUI;
typedef __attribute__((address_space(3))) unsigned int LUI;

// ---------------------------------------------------------------------------
// Kernel 1: nested dequant of HQQ 4-bit weights -> bf16 [OUT_F][IN_F]
// ---------------------------------------------------------------------------
__global__ __launch_bounds__(256) void dequant_w_kernel(
    const int* __restrict__ Wq, const int* __restrict__ sq, const int* __restrict__ zq,
    const float* __restrict__ ss, const float* __restrict__ zs,
    const float* __restrict__ sz, const float* __restrict__ zz,
    unsigned short* __restrict__ Wb)
{
    int tid = blockIdx.x * blockDim.x + threadIdx.x;
    int g = tid >> 3;
    int off = (tid & 7) << 3;

    float scale = ((float)sq[g] - zs[0]) * ss[0];
    float zero  = ((float)zq[g] - zz[0]) * sz[0];

    const int4* p = reinterpret_cast<const int4*>(Wq + ((size_t)g << 6) + off);
    int4 q0 = p[0], q1 = p[1];
    int qs[8] = {q0.x, q0.y, q0.z, q0.w, q1.x, q1.y, q1.z, q1.w};

    unsigned short w[8];
#pragma unroll
    for (int j = 0; j < 8; ++j) {
        __hip_bfloat16 b = __float2bfloat16(((float)qs[j] - zero) * scale);
        w[j] = *reinterpret_cast<unsigned short*>(&b);
    }
    *reinterpret_cast<int4*>(Wb + ((size_t)g << 6) + off) =
        *reinterpret_cast<int4*>(w);
}

// ---------------------------------------------------------------------------
// Kernel 2: x fp32 -> bf16
// ---------------------------------------------------------------------------
__global__ __launch_bounds__(256) void convert_x_kernel(
    const float* __restrict__ x, unsigned short* __restrict__ xb)
{
    size_t tid = (size_t)blockIdx.x * blockDim.x + threadIdx.x;
    size_t base = tid << 3;
    const float4* p = reinterpret_cast<const float4*>(x + base);
    float4 f0 = p[0], f1 = p[1];
    float fs[8] = {f0.x, f0.y, f0.z, f0.w, f1.x, f1.y, f1.z, f1.w};
    unsigned short w[8];
#pragma unroll
    for (int j = 0; j < 8; ++j) {
        __hip_bfloat16 b = __float2bfloat16(fs[j]);
        w[j] = *reinterpret_cast<unsigned short*>(&b);
    }
    *reinterpret_cast<int4*>(xb + base) = *reinterpret_cast<int4*>(w);
}

// ---------------------------------------------------------------------------
// Kernel 3: 256x256 bf16 GEMM — ROUND-4 sync structure (verified), MFMA shape
// switched to 32x32x16 (+20% pipe rate, half the MFMA issue count).
//   C[M][N] = A[M][K] * B[N][K]^T + bias
// 8 waves (2M x 4N), wave tile 128x64 = 4 Mblk x 2 Nblk of 32x32.
// Per K-tile, 4 phases (1 barrier each), round-4 ledger verbatim:
//   P0: BAR; read A(mb0,1)+B(nb0) [12 ds_reads]; lgkm0; 8 MFMA;
//       tail: read B(nb1); stage B1(k+1)->D^1
//   P1: BAR; lgkm0; 8 MFMA; tail: read A(mb2,3); stage A1(k+1)->D^1
//   P2: BAR; lgkm0; 8 MFMA; tail: stage B0(k+2)->D
//   P3: BAR; 8 MFMA (regs); tail: stage A0(k+2)->D; vmcnt(4)
// vmcnt(4) once per K-tile, never 0 in the main loop.
// LDS unchanged: byte(row,slot)=row*128+(slot^(row&7))*16, pre-swizzled src.
// 32x32x16 frags: row=lane&31, k-chunk=lane>>5 -> slot idx = ks*2+(lane>>5).
// Conflict-free: each aligned 8-lane group covers 8 distinct 16B slots.
// ---------------------------------------------------------------------------
__global__ __launch_bounds__(512, 2) void gemm_bf16_kernel(
    const unsigned short* __restrict__ A,   // [M][K] bf16
    const unsigned short* __restrict__ B,   // [N][K] bf16
    const float* __restrict__ bias,
    float* __restrict__ C)
{
    __shared__ __align__(16) char lds[131072];

    const int K = IN_F;

    // T1: bijective XCD swizzle (512 blocks, 8 XCDs)
    int bid = blockIdx.x;
    int swz = (bid & 7) * 64 + (bid >> 3);
    int bx = swz & 15;           // 16 N-tiles
    int by = swz >> 4;           // 32 M-tiles

    int tid = threadIdx.x;
    int lane = tid & 63;
    int wid = tid >> 6;
    int wr = wid >> 2;           // 0..1 (M)
    int wc = wid & 3;            // 0..3 (N)

    // staging addressing (linear LDS dest; pre-swizzled global source)
    int roff = tid >> 3;                                  // 0..63
    int soff = (((tid & 7) ^ ((tid >> 3) & 7)) << 3);     // src k-elem offset
    const unsigned short* srcA = A + (size_t)(by * BM + roff) * K + soff;
    const unsigned short* srcB = B + (size_t)(bx * BN + roff) * K + soff;

#define STAGE_A(kt, h, D2) do {                                               \
    __builtin_amdgcn_global_load_lds(                                         \
        (GUI*)(srcA + (size_t)((h)*128) * IN_F + (size_t)(kt) * BK),          \
        (LUI*)(lds + (D2)*32768 + (h)*16384 + wid*1024), 16, 0, 0);           \
    __builtin_amdgcn_global_load_lds(                                         \
        (GUI*)(srcA + (size_t)((h)*128 + 64) * IN_F + (size_t)(kt) * BK),     \
        (LUI*)(lds + (D2)*32768 + (h)*16384 + 8192 + wid*1024), 16, 0, 0);    \
    } while (0)
#define STAGE_B(kt, h, D2) do {                                               \
    __builtin_amdgcn_global_load_lds(                                         \
        (GUI*)(srcB + (size_t)((h)*128) * IN_F + (size_t)(kt) * BK),          \
        (LUI*)(lds + 65536 + (D2)*32768 + (h)*16384 + wid*1024), 16, 0, 0);   \
    __builtin_amdgcn_global_load_lds(                                         \
        (GUI*)(srcB + (size_t)((h)*128 + 64) * IN_F + (size_t)(kt) * BK),     \
        (LUI*)(lds + 65536 + (D2)*32768 + (h)*16384 + 8192 + wid*1024),       \
        16, 0, 0);                                                            \
    } while (0)

    // ---- 32x32x16 fragment read addressing (swizzled) ----
    int l31 = lane & 31;          // row within 32-block
    int kgrp = lane >> 5;         // 0..1 (k-chunk of 8)
    // physical 16B-slot for k-step ks: (ks*2 + kgrp) ^ (row&7); row&7 == lane&7
    int sb[4];
#pragma unroll
    for (int ks = 0; ks < 4; ++ks)
        sb[ks] = (((ks * 2 + kgrp) ^ (lane & 7)) << 4);
    // A: buffer half = wr; row within half = mb*32 + l31
    int aBase = wr * 16384 + l31 * 128;
    // B: buffer half = wc>>1; row within half = (wc&1)*64 + nb*32 + l31
    int bBase = (wc >> 1) * 16384 + ((wc & 1) * 64 + l31) * 128;

#define RA(D2, mb, ks) (*(const bf16x8*)(lds + (D2)*32768 + aBase +           \
        (mb)*4096 + sb[ks]))
#define RB(D2, nb, ks) (*(const bf16x8*)(lds + 65536 + (D2)*32768 + bBase +   \
        (nb)*4096 + sb[ks]))

    f32x16 acc[4][2] = {};        // [Mblk][Nblk]
    bf16x8 aF[2][4], bF0[4], bF1[4];

#define FENCE asm volatile("" ::: "memory")
#define WAIT_LGKM asm volatile("s_waitcnt lgkmcnt(0)" ::: "memory")
#define BARRIER asm volatile("s_barrier" ::: "memory")

#define KTILE(kt, D, S01, S23, VM) do {                                       \
    /* -------- P0: Mblk{0,1} x Nblk0; opening reads post-barrier -------- */ \
    BARRIER;                                                                  \
    _Pragma("unroll") for (int q = 0; q < 2; ++q)                             \
    _Pragma("unroll") for (int ks = 0; ks < 4; ++ks)                          \
        aF[q][ks] = RA(D, q, ks);                                             \
    _Pragma("unroll") for (int ks = 0; ks < 4; ++ks)                          \
        bF0[ks] = RB(D, 0, ks);                                               \
    WAIT_LGKM;                                                                \
    __builtin_amdgcn_s_setprio(1);                                            \
    _Pragma("unroll") for (int q = 0; q < 2; ++q)                             \
    _Pragma("unroll") for (int ks = 0; ks < 4; ++ks)                          \
        acc[q][0] = __builtin_amdgcn_mfma_f32_32x32x16_bf16(                  \
            aF[q][ks], bF0[ks], acc[q][0], 0, 0, 0);                          \
    __builtin_amdgcn_s_setprio(0);                                            \
    /* P0 tail: read bF1(kt); stage B1(kt+1) */                               \
    _Pragma("unroll") for (int ks = 0; ks < 4; ++ks)                          \
        bF1[ks] = RB(D, 1, ks);                                               \
    if (S01) STAGE_B((kt) + 1, 1, (D) ^ 1);                                   \
    FENCE;                                                                    \
    /* -------- P1: Mblk{0,1} x Nblk1 ------------------------------------ */ \
    BARRIER;                                                                  \
    WAIT_LGKM;                                                                \
    __builtin_amdgcn_s_setprio(1);                                            \
    _Pragma("unroll") for (int q = 0; q < 2; ++q)                             \
    _Pragma("unroll") for (int ks = 0; ks < 4; ++ks)                          \
        acc[q][1] = __builtin_amdgcn_mfma_f32_32x32x16_bf16(                  \
            aF[q][ks], bF1[ks], acc[q][1], 0, 0, 0);                          \
    __builtin_amdgcn_s_setprio(0);                                            \
    /* P1 tail: read A Mblk{2,3} (overwrites aF); stage A1(kt+1) */           \
    _Pragma("unroll") for (int q = 0; q < 2; ++q)                             \
    _Pragma("unroll") for (int ks = 0; ks < 4; ++ks)                          \
        aF[q][ks] = RA(D, 2 + q, ks);                                         \
    if (S01) STAGE_A((kt) + 1, 1, (D) ^ 1);                                   \
    FENCE;                                                                    \
    /* -------- P2: Mblk{2,3} x Nblk0 ------------------------------------ */ \
    BARRIER;                                                                  \
    WAIT_LGKM;                                                                \
    __builtin_amdgcn_s_setprio(1);                                            \
    _Pragma("unroll") for (int q = 0; q < 2; ++q)                             \
    _Pragma("unroll") for (int ks = 0; ks < 4; ++ks)                          \
        acc[2 + q][0] = __builtin_amdgcn_mfma_f32_32x32x16_bf16(              \
            aF[q][ks], bF0[ks], acc[2 + q][0], 0, 0, 0);                      \
    __builtin_amdgcn_s_setprio(0);                                            \
    /* P2 tail: stage B0(kt+2) */                                             \
    if (S23) STAGE_B((kt) + 2, 0, D);                                         \
    FENCE;                                                                    \
    /* -------- P3: Mblk{2,3} x Nblk1; operands already in regs ---------- */ \
    BARRIER;                                                                  \
    __builtin_amdgcn_s_setprio(1);                                            \
    _Pragma("unroll") for (int q = 0; q < 2; ++q)                             \
    _Pragma("unroll") for (int ks = 0; ks < 4; ++ks)                          \
        acc[2 + q][1] = __builtin_amdgcn_mfma_f32_32x32x16_bf16(              \
            aF[q][ks], bF1[ks], acc[2 + q][1], 0, 0, 0);                      \
    __builtin_amdgcn_s_setprio(0);                                            \
    /* P3 tail: stage A0(kt+2); counted vmcnt */                              \
    if (S23) STAGE_A((kt) + 2, 0, D);                                         \
    if ((VM) == 4) asm volatile("s_waitcnt vmcnt(4)" ::: "memory");           \
    else if ((VM) == 0) asm volatile("s_waitcnt vmcnt(0)" ::: "memory");      \
    FENCE;                                                                    \
    } while (0)

    // prologue: tile 0 fully + h0 of tile 1 (12 loads/thread);
    // vmcnt(4) completes all of tile 0, leaves B0(1),A0(1) pending.
    STAGE_B(0, 0, 0); STAGE_A(0, 0, 0);
    STAGE_B(0, 1, 0); STAGE_A(0, 1, 0);
    STAGE_B(1, 0, 1); STAGE_A(1, 0, 1);
    asm volatile("s_waitcnt vmcnt(4)" ::: "memory");
    BARRIER;

    for (int t = 0; t < (NT - 2) / 2; ++t) {   // k = 0 .. 61
        KTILE(2 * t, 0, 1, 1, 4);
        KTILE(2 * t + 1, 1, 1, 1, 4);
    }
    KTILE(NT - 2, 0, 1, 0, 0);                 // k = 62: stage h1(63), drain
    KTILE(NT - 1, 1, 0, 0, -1);                // k = 63: compute only

    // ---- epilogue: 32x32x16 C/D layout (m74/m101):
    // col = lane&31, row = (reg&3) + 8*(reg>>2) + 4*(lane>>5)
    int colBase = bx * BN + wc * 64 + l31;
    int rowBase = by * BM + wr * 128 + 4 * kgrp;
#pragma unroll
    for (int nb = 0; nb < 2; ++nb) {
        int col = colBase + nb * 32;
        float bv = bias[col];
#pragma unroll
        for (int mb = 0; mb < 4; ++mb) {
#pragma unroll
            for (int r = 0; r < 16; ++r) {
                int row = rowBase + mb * 32 + (r & 3) + 8 * (r >> 2);
                C[(size_t)row * OUT_F + col] = acc[mb][nb][r] + bv;
            }
        }
    }
#undef KTILE
#undef FENCE
#undef WAIT_LGKM
#undef BARRIER
#undef RA
#undef RB
#undef STAGE_A
#undef STAGE_B
}

// ---------------------------------------------------------------------------
extern "C" void kernel_launch(void* const* d_in, const int* in_sizes, int n_in,
                              void* d_out, int out_size, void* d_ws, size_t ws_size,
                              hipStream_t stream) {
    const float* x      = (const float*)d_in[0];
    const int*   Wq     = (const int*)d_in[1];
    const int*   sq     = (const int*)d_in[2];
    const int*   zq     = (const int*)d_in[3];
    const float* ss     = (const float*)d_in[4];
    const float* zs     = (const float*)d_in[5];
    const float* sz     = (const float*)d_in[6];
    const float* zz     = (const float*)d_in[7];
    const float* bias   = (const float*)d_in[8];
    float* out = (float*)d_out;

    unsigned short* xb = (unsigned short*)d_ws;
    unsigned short* Wb = (unsigned short*)((char*)d_ws + (size_t)M_ROWS * IN_F * 2);

    dequant_w_kernel<<<8192, 256, 0, stream>>>(Wq, sq, zq, ss, zs, sz, zz, Wb);
    convert_x_kernel<<<16384, 256, 0, stream>>>(x, xb);
    gemm_bf16_kernel<<<512, 512, 0, stream>>>(xb, Wb, bias, out);
}

// Round 8
// 287.029 us; speedup vs baseline: 1.0088x; 1.0088x over previous
//
#include <hip/hip_runtime.h>
#include <hip/hip_bf16.h>

#define IN_F 4096
#define OUT_F 4096
#define M_ROWS 8192

#define BM 256
#define BN 256
#define BK 64
#define NT 64                  // IN_F / BK K-tiles

typedef __attribute__((ext_vector_type(8))) __bf16 bf16x8;
typedef __attribute__((ext_vector_type(16))) float f32x16;
typedef __attribute__((address_space(1))) const unsigned int GUI;
typedef __attribute__((address_space(3))) unsigned int LUI;

// ---------------------------------------------------------------------------
// Kernel 1: nested dequant of HQQ 4-bit weights -> bf16 [OUT_F][IN_F]
// ---------------------------------------------------------------------------
__global__ __launch_bounds__(256) void dequant_w_kernel(
    const int* __restrict__ Wq, const int* __restrict__ sq, const int* __restrict__ zq,
    const float* __restrict__ ss, const float* __restrict__ zs,
    const float* __restrict__ sz, const float* __restrict__ zz,
    unsigned short* __restrict__ Wb)
{
    int tid = blockIdx.x * blockDim.x + threadIdx.x;
    int g = tid >> 3;
    int off = (tid & 7) << 3;

    float scale = ((float)sq[g] - zs[0]) * ss[0];
    float zero  = ((float)zq[g] - zz[0]) * sz[0];

    const int4* p = reinterpret_cast<const int4*>(Wq + ((size_t)g << 6) + off);
    int4 q0 = p[0], q1 = p[1];
    int qs[8] = {q0.x, q0.y, q0.z, q0.w, q1.x, q1.y, q1.z, q1.w};

    unsigned short w[8];
#pragma unroll
    for (int j = 0; j < 8; ++j) {
        __hip_bfloat16 b = __float2bfloat16(((float)qs[j] - zero) * scale);
        w[j] = *reinterpret_cast<unsigned short*>(&b);
    }
    *reinterpret_cast<int4*>(Wb + ((size_t)g << 6) + off) =
        *reinterpret_cast<int4*>(w);
}

// ---------------------------------------------------------------------------
// Kernel 2: x fp32 -> bf16
// ---------------------------------------------------------------------------
__global__ __launch_bounds__(256) void convert_x_kernel(
    const float* __restrict__ x, unsigned short* __restrict__ xb)
{
    size_t tid = (size_t)blockIdx.x * blockDim.x + threadIdx.x;
    size_t base = tid << 3;
    const float4* p = reinterpret_cast<const float4*>(x + base);
    float4 f0 = p[0], f1 = p[1];
    float fs[8] = {f0.x, f0.y, f0.z, f0.w, f1.x, f1.y, f1.z, f1.w};
    unsigned short w[8];
#pragma unroll
    for (int j = 0; j < 8; ++j) {
        __hip_bfloat16 b = __float2bfloat16(fs[j]);
        w[j] = *reinterpret_cast<unsigned short*>(&b);
    }
    *reinterpret_cast<int4*>(xb + base) = *reinterpret_cast<int4*>(w);
}

// ---------------------------------------------------------------------------
// Kernel 3: 256x256 bf16 GEMM, 32x32x16 MFMA, ROUND-4 sync structure.
//   C[M][N] = A[M][K] * B[N][K]^T + bias
// LDS LAYOUT (round-8 conflict fix): per 16KB half-tile (128 rows x 8
// k-granules of 16B), granule (row,kc) lives at
//   line  = (row&15) + 16*(row>>5) + 64*(kc>>2)      (128B lines)
//   lslot = (kc&3) + 4*((row>>4)&1)
//   pslot = lslot ^ (line&7)        ; byte = line*128 + pslot*16
// => a 32x32 frag read (mb,ks) touches 16 lines x 4 lanes/line with 4
// distinct slots per line, consecutive-8 lanes hit 8 lines at 8 distinct
// bank-quads — identical profile to the round-4 pattern that measured 0
// conflicts (round-7's 32-rows-per-instruction pattern measured 2.5e7).
// Staging: thread t stages granules (row0,kc0) and (row0,kc0+4), where
//   ls0 = (t&7)^((t>>3)&7); row0 = ((t>>3)&15) + 16*((ls0>>2)&1) + 32*(t>>7);
//   kc0 = ls0&3   — linear LDS dest (granule G = t, 512+t), per-lane source.
// Sync/phases/vmcnt: round-4 ledger verbatim (verified twice on HW).
// ---------------------------------------------------------------------------
__global__ __launch_bounds__(512, 2) void gemm_bf16_kernel(
    const unsigned short* __restrict__ A,   // [M][K] bf16
    const unsigned short* __restrict__ B,   // [N][K] bf16
    const float* __restrict__ bias,
    float* __restrict__ C)
{
    __shared__ __align__(16) char lds[131072];

    const int K = IN_F;

    // T1: bijective XCD swizzle (512 blocks, 8 XCDs)
    int bid = blockIdx.x;
    int swz = (bid & 7) * 64 + (bid >> 3);
    int bx = swz & 15;           // 16 N-tiles
    int by = swz >> 4;           // 32 M-tiles

    int tid = threadIdx.x;
    int lane = tid & 63;
    int wid = tid >> 6;
    int wr = wid >> 2;           // 0..1 (M)
    int wc = wid & 3;            // 0..3 (N)

    // ---- staging source addressing (per-thread granule mapping) ----
    int ls0  = (tid & 7) ^ ((tid >> 3) & 7);
    int row0 = ((tid >> 3) & 15) + 16 * ((ls0 >> 2) & 1) + 32 * (tid >> 7);
    int kc0  = ls0 & 3;
    const unsigned short* srcA = A + (size_t)(by * BM + row0) * K + kc0 * 8;
    const unsigned short* srcB = B + (size_t)(bx * BN + row0) * K + kc0 * 8;

#define STAGE_A(kt, h, D2) do {                                               \
    __builtin_amdgcn_global_load_lds(                                         \
        (GUI*)(srcA + (size_t)((h)*128) * IN_F + (size_t)(kt) * BK),          \
        (LUI*)(lds + (D2)*32768 + (h)*16384 + wid*1024), 16, 0, 0);           \
    __builtin_amdgcn_global_load_lds(                                         \
        (GUI*)(srcA + (size_t)((h)*128) * IN_F + (size_t)(kt) * BK + 32),     \
        (LUI*)(lds + (D2)*32768 + (h)*16384 + 8192 + wid*1024), 16, 0, 0);    \
    } while (0)
#define STAGE_B(kt, h, D2) do {                                               \
    __builtin_amdgcn_global_load_lds(                                         \
        (GUI*)(srcB + (size_t)((h)*128) * IN_F + (size_t)(kt) * BK),          \
        (LUI*)(lds + 65536 + (D2)*32768 + (h)*16384 + wid*1024), 16, 0, 0);   \
    __builtin_amdgcn_global_load_lds(                                         \
        (GUI*)(srcB + (size_t)((h)*128) * IN_F + (size_t)(kt) * BK + 32),     \
        (LUI*)(lds + 65536 + (D2)*32768 + (h)*16384 + 8192 + wid*1024),       \
        16, 0, 0);                                                            \
    } while (0)

    // ---- 32x32x16 fragment read addressing (new layout) ----
    int l31 = lane & 31;          // row within 32-block
    int kgrp = lane >> 5;         // 0..1 (k-chunk of 8)
    int sb2[4];
#pragma unroll
    for (int ks = 0; ks < 4; ++ks)
        sb2[ks] = (((((2 * ks + kgrp) & 3) | (((l31 >> 4) & 1) << 2))
                    ^ (l31 & 7)) << 4);
    int rowb = (l31 & 15) * 128;
    int aBase = wr * 16384 + rowb;
    int bBase = (wc >> 1) * 16384 + rowb;

#define RA(D2, mb, ks) (*(const bf16x8*)(lds + (D2)*32768 + aBase +           \
        (mb)*2048 + ((ks) >> 1)*8192 + sb2[ks]))
#define RB(D2, nb, ks) (*(const bf16x8*)(lds + 65536 + (D2)*32768 + bBase +   \
        (((wc & 1) * 2 + (nb)))*2048 + ((ks) >> 1)*8192 + sb2[ks]))

    f32x16 acc[4][2] = {};        // [Mblk][Nblk]
    bf16x8 aF[2][4], bF0[4], bF1[4];

#define FENCE asm volatile("" ::: "memory")
#define WAIT_LGKM asm volatile("s_waitcnt lgkmcnt(0)" ::: "memory")
#define BARRIER asm volatile("s_barrier" ::: "memory")

#define KTILE(kt, D, S01, S23, VM) do {                                       \
    /* -------- P0: Mblk{0,1} x Nblk0; opening reads post-barrier -------- */ \
    BARRIER;                                                                  \
    _Pragma("unroll") for (int q = 0; q < 2; ++q)                             \
    _Pragma("unroll") for (int ks = 0; ks < 4; ++ks)                          \
        aF[q][ks] = RA(D, q, ks);                                             \
    _Pragma("unroll") for (int ks = 0; ks < 4; ++ks)                          \
        bF0[ks] = RB(D, 0, ks);                                               \
    WAIT_LGKM;                                                                \
    __builtin_amdgcn_s_setprio(1);                                            \
    _Pragma("unroll") for (int q = 0; q < 2; ++q)                             \
    _Pragma("unroll") for (int ks = 0; ks < 4; ++ks)                          \
        acc[q][0] = __builtin_amdgcn_mfma_f32_32x32x16_bf16(                  \
            aF[q][ks], bF0[ks], acc[q][0], 0, 0, 0);                          \
    __builtin_amdgcn_s_setprio(0);                                            \
    /* P0 tail: read bF1(kt); stage B1(kt+1) */                               \
    _Pragma("unroll") for (int ks = 0; ks < 4; ++ks)                          \
        bF1[ks] = RB(D, 1, ks);                                               \
    if (S01) STAGE_B((kt) + 1, 1, (D) ^ 1);                                   \
    FENCE;                                                                    \
    /* -------- P1: Mblk{0,1} x Nblk1 ------------------------------------ */ \
    BARRIER;                                                                  \
    WAIT_LGKM;                                                                \
    __builtin_amdgcn_s_setprio(1);                                            \
    _Pragma("unroll") for (int q = 0; q < 2; ++q)                             \
    _Pragma("unroll") for (int ks = 0; ks < 4; ++ks)                          \
        acc[q][1] = __builtin_amdgcn_mfma_f32_32x32x16_bf16(                  \
            aF[q][ks], bF1[ks], acc[q][1], 0, 0, 0);                          \
    __builtin_amdgcn_s_setprio(0);                                            \
    /* P1 tail: read A Mblk{2,3} (overwrites aF); stage A1(kt+1) */           \
    _Pragma("unroll") for (int q = 0; q < 2; ++q)                             \
    _Pragma("unroll") for (int ks = 0; ks < 4; ++ks)                          \
        aF[q][ks] = RA(D, 2 + q, ks);                                         \
    if (S01) STAGE_A((kt) + 1, 1, (D) ^ 1);                                   \
    FENCE;                                                                    \
    /* -------- P2: Mblk{2,3} x Nblk0 ------------------------------------ */ \
    BARRIER;                                                                  \
    WAIT_LGKM;                                                                \
    __builtin_amdgcn_s_setprio(1);                                            \
    _Pragma("unroll") for (int q = 0; q < 2; ++q)                             \
    _Pragma("unroll") for (int ks = 0; ks < 4; ++ks)                          \
        acc[2 + q][0] = __builtin_amdgcn_mfma_f32_32x32x16_bf16(              \
            aF[q][ks], bF0[ks], acc[2 + q][0], 0, 0, 0);                      \
    __builtin_amdgcn_s_setprio(0);                                            \
    /* P2 tail: stage B0(kt+2) */                                             \
    if (S23) STAGE_B((kt) + 2, 0, D);                                         \
    FENCE;                                                                    \
    /* -------- P3: Mblk{2,3} x Nblk1; operands already in regs ---------- */ \
    BARRIER;                                                                  \
    __builtin_amdgcn_s_setprio(1);                                            \
    _Pragma("unroll") for (int q = 0; q < 2; ++q)                             \
    _Pragma("unroll") for (int ks = 0; ks < 4; ++ks)                          \
        acc[2 + q][1] = __builtin_amdgcn_mfma_f32_32x32x16_bf16(              \
            aF[q][ks], bF1[ks], acc[2 + q][1], 0, 0, 0);                      \
    __builtin_amdgcn_s_setprio(0);                                            \
    /* P3 tail: stage A0(kt+2); counted vmcnt */                              \
    if (S23) STAGE_A((kt) + 2, 0, D);                                         \
    if ((VM) == 4) asm volatile("s_waitcnt vmcnt(4)" ::: "memory");           \
    else if ((VM) == 0) asm volatile("s_waitcnt vmcnt(0)" ::: "memory");      \
    FENCE;                                                                    \
    } while (0)

    // prologue: tile 0 fully + h0 of tile 1 (12 loads/thread);
    // vmcnt(4) completes all of tile 0, leaves B0(1),A0(1) pending.
    STAGE_B(0, 0, 0); STAGE_A(0, 0, 0);
    STAGE_B(0, 1, 0); STAGE_A(0, 1, 0);
    STAGE_B(1, 0, 1); STAGE_A(1, 0, 1);
    asm volatile("s_waitcnt vmcnt(4)" ::: "memory");
    BARRIER;

    for (int t = 0; t < (NT - 2) / 2; ++t) {   // k = 0 .. 61
        KTILE(2 * t, 0, 1, 1, 4);
        KTILE(2 * t + 1, 1, 1, 1, 4);
    }
    KTILE(NT - 2, 0, 1, 0, 0);                 // k = 62: stage h1(63), drain
    KTILE(NT - 1, 1, 0, 0, -1);                // k = 63: compute only

    // ---- epilogue: 32x32x16 C/D layout (m74/m101):
    // col = lane&31, row = (reg&3) + 8*(reg>>2) + 4*(lane>>5)
    int colBase = bx * BN + wc * 64 + l31;
    int rowBase = by * BM + wr * 128 + 4 * kgrp;
#pragma unroll
    for (int nb = 0; nb < 2; ++nb) {
        int col = colBase + nb * 32;
        float bv = bias[col];
#pragma unroll
        for (int mb = 0; mb < 4; ++mb) {
#pragma unroll
            for (int r = 0; r < 16; ++r) {
                int row = rowBase + mb * 32 + (r & 3) + 8 * (r >> 2);
                C[(size_t)row * OUT_F + col] = acc[mb][nb][r] + bv;
            }
        }
    }
#undef KTILE
#undef FENCE
#undef WAIT_LGKM
#undef BARRIER
#undef RA
#undef RB
#undef STAGE_A
#undef STAGE_B
}

// ---------------------------------------------------------------------------
extern "C" void kernel_launch(void* const* d_in, const int* in_sizes, int n_in,
                              void* d_out, int out_size, void* d_ws, size_t ws_size,
                              hipStream_t stream) {
    const float* x      = (const float*)d_in[0];
    const int*   Wq     = (const int*)d_in[1];
    const int*   sq     = (const int*)d_in[2];
    const int*   zq     = (const int*)d_in[3];
    const float* ss     = (const float*)d_in[4];
    const float* zs     = (const float*)d_in[5];
    const float* sz     = (const float*)d_in[6];
    const float* zz     = (const float*)d_in[7];
    const float* bias   = (const float*)d_in[8];
    float* out = (float*)d_out;

    unsigned short* xb = (unsigned short*)d_ws;
    unsigned short* Wb = (unsigned short*)((char*)d_ws + (size_t)M_ROWS * IN_F * 2);

    dequant_w_kernel<<<8192, 256, 0, stream>>>(Wq, sq, zq, ss, zs, sz, zz, Wb);
    convert_x_kernel<<<16384, 256, 0, stream>>>(x, xb);
    gemm_bf16_kernel<<<512, 512, 0, stream>>>(xb, Wb, bias, out);
}

// Round 9
// 258.786 us; speedup vs baseline: 1.1189x; 1.1091x over previous
//
#include <hip/hip_runtime.h>
#include <hip/hip_bf16.h>

#define IN_F 4096
#define OUT_F 4096
#define M_ROWS 8192

#define BM 256
#define BN 256
#define BK 64
#define NT 64                  // IN_F / BK K-tiles

typedef __attribute__((ext_vector_type(8))) __bf16 bf16x8;
typedef __attribute__((ext_vector_type(4))) float f32x4;
typedef __attribute__((address_space(1))) const unsigned int GUI;
typedef __attribute__((address_space(3))) unsigned int LUI;

// ---------------------------------------------------------------------------
// Kernel 1 (merged prep): HQQ nested dequant Wq->bf16  AND  x fp32->bf16.
// Grid-stride over both independent domains; 2048 blocks x 256 threads.
// ---------------------------------------------------------------------------
__global__ __launch_bounds__(256) void prep_kernel(
    const float* __restrict__ x,
    const int* __restrict__ Wq, const int* __restrict__ sq, const int* __restrict__ zq,
    const float* __restrict__ ss, const float* __restrict__ zs,
    const float* __restrict__ sz, const float* __restrict__ zz,
    unsigned short* __restrict__ xb, unsigned short* __restrict__ Wb)
{
    const int nth = gridDim.x * blockDim.x;
    const int tid0 = blockIdx.x * blockDim.x + threadIdx.x;
    const float s_scale = ss[0], z_scale = zs[0], s_zero = sz[0], z_zero = zz[0];

    // ---- dequant W: 262144 groups x 8 jobs (8 elems/job, 32B in / 16B out)
    for (int tid = tid0; tid < (1 << 21); tid += nth) {
        int g = tid >> 3;
        int off = (tid & 7) << 3;
        float scale = ((float)sq[g] - z_scale) * s_scale;
        float zero  = ((float)zq[g] - z_zero) * s_zero;

        const int4* p = reinterpret_cast<const int4*>(Wq + ((size_t)g << 6) + off);
        int4 q0 = p[0], q1 = p[1];
        int qs[8] = {q0.x, q0.y, q0.z, q0.w, q1.x, q1.y, q1.z, q1.w};
        unsigned short w[8];
#pragma unroll
        for (int j = 0; j < 8; ++j) {
            __hip_bfloat16 b = __float2bfloat16(((float)qs[j] - zero) * scale);
            w[j] = *reinterpret_cast<unsigned short*>(&b);
        }
        *reinterpret_cast<int4*>(Wb + ((size_t)g << 6) + off) =
            *reinterpret_cast<int4*>(w);
    }

    // ---- convert x: 4,194,304 jobs (8 elems/job, 32B in / 16B out)
    for (size_t tid = tid0; tid < (size_t)(1 << 22); tid += nth) {
        size_t base = tid << 3;
        const float4* p = reinterpret_cast<const float4*>(x + base);
        float4 f0 = p[0], f1 = p[1];
        float fs[8] = {f0.x, f0.y, f0.z, f0.w, f1.x, f1.y, f1.z, f1.w};
        unsigned short w[8];
#pragma unroll
        for (int j = 0; j < 8; ++j) {
            __hip_bfloat16 b = __float2bfloat16(fs[j]);
            w[j] = *reinterpret_cast<unsigned short*>(&b);
        }
        *reinterpret_cast<int4*>(xb + base) = *reinterpret_cast<int4*>(w);
    }
}

// ---------------------------------------------------------------------------
// Kernel 2: 256x256 bf16 GEMM — ROUND-4 VERIFIED KERNEL, VERBATIM.
//   C[M][N] = A[M][K] * B[N][K]^T + bias
// 8 waves (2M x 4N), wave tile 128x64, BK=64, double-buffered LDS (128 KiB).
// 16x16x32 MFMA. 1 barrier per phase, rotated tails, vmcnt(4) once per
// K-tile (never 0 in main loop). Measured: 215 us, MfmaUtil 59%, conflicts 0.
// ---------------------------------------------------------------------------
__global__ __launch_bounds__(512, 2) void gemm_bf16_kernel(
    const unsigned short* __restrict__ A,   // [M][K] bf16
    const unsigned short* __restrict__ B,   // [N][K] bf16
    const float* __restrict__ bias,
    float* __restrict__ C)
{
    // LDS: A bufs [0,64K), B bufs [64K,128K). Buf = 2 halves x 128 rows x 128B.
    // byte(row, slot) = row*128 + (slot^(row&7))*16.
    __shared__ __align__(16) char lds[131072];

    const int K = IN_F;

    // T1: bijective XCD swizzle (512 blocks, 8 XCDs)
    int bid = blockIdx.x;
    int swz = (bid & 7) * 64 + (bid >> 3);
    int bx = swz & 15;           // 16 N-tiles
    int by = swz >> 4;           // 32 M-tiles

    int tid = threadIdx.x;
    int lane = tid & 63;
    int wid = tid >> 6;
    int wr = wid >> 2;           // 0..1 (M)
    int wc = wid & 3;            // 0..3 (N)

    // staging addressing (linear LDS dest; pre-swizzled global source)
    int roff = tid >> 3;                                  // 0..63
    int soff = (((tid & 7) ^ ((tid >> 3) & 7)) << 3);     // src k-elem offset
    const unsigned short* srcA = A + (size_t)(by * BM + roff) * K + soff;
    const unsigned short* srcB = B + (size_t)(bx * BN + roff) * K + soff;

#define STAGE_A(kt, h, D2) do {                                               \
    __builtin_amdgcn_global_load_lds(                                         \
        (GUI*)(srcA + (size_t)((h)*128) * IN_F + (size_t)(kt) * BK),          \
        (LUI*)(lds + (D2)*32768 + (h)*16384 + wid*1024), 16, 0, 0);           \
    __builtin_amdgcn_global_load_lds(                                         \
        (GUI*)(srcA + (size_t)((h)*128 + 64) * IN_F + (size_t)(kt) * BK),     \
        (LUI*)(lds + (D2)*32768 + (h)*16384 + 8192 + wid*1024), 16, 0, 0);    \
    } while (0)
#define STAGE_B(kt, h, D2) do {                                               \
    __builtin_amdgcn_global_load_lds(                                         \
        (GUI*)(srcB + (size_t)((h)*128) * IN_F + (size_t)(kt) * BK),          \
        (LUI*)(lds + 65536 + (D2)*32768 + (h)*16384 + wid*1024), 16, 0, 0);   \
    __builtin_amdgcn_global_load_lds(                                         \
        (GUI*)(srcB + (size_t)((h)*128 + 64) * IN_F + (size_t)(kt) * BK),     \
        (LUI*)(lds + 65536 + (D2)*32768 + (h)*16384 + 8192 + wid*1024),       \
        16, 0, 0);                                                            \
    } while (0)

    // fragment read addressing (swizzled)
    int lr = lane & 15;
    int kq = lane >> 4;                       // 0..3
    int cslot = (kq ^ (lr & 3)) << 4;
    int offk0 = ((lr >> 2) & 1) << 6;
    int offk1 = 64 - offk0;
    int aRd = (wr * 128 + lr) * 128 + cslot;
    int bRd = (wc * 64 + lr) * 128 + cslot;

#define RDA(D2, h, m, ks) (*(const bf16x8*)(lds + (D2)*32768 + aRd +          \
        (h)*8192 + (m)*2048 + ((ks) ? offk1 : offk0)))
#define RDB(D2, c, n, ks) (*(const bf16x8*)(lds + 65536 + (D2)*32768 + bRd +  \
        (c)*4096 + (n)*2048 + ((ks) ? offk1 : offk0)))

    f32x4 acc[8][4] = {};
    bf16x8 a[4][2], b0[2][2], b1[2][2];

#define FENCE asm volatile("" ::: "memory")
#define WAIT_LGKM asm volatile("s_waitcnt lgkmcnt(0)" ::: "memory")

#define KTILE(kt, D, S01, S23, VM) do {                                       \
    /* -------- P0: quadrant (h=0,c=0); opening reads post-barrier ------- */ \
    __builtin_amdgcn_s_barrier();                                             \
    _Pragma("unroll") for (int m = 0; m < 4; ++m) {                           \
        a[m][0] = RDA(D, 0, m, 0); a[m][1] = RDA(D, 0, m, 1); }               \
    _Pragma("unroll") for (int n = 0; n < 2; ++n) {                           \
        b0[n][0] = RDB(D, 0, n, 0); b0[n][1] = RDB(D, 0, n, 1); }             \
    WAIT_LGKM;                                                                \
    __builtin_amdgcn_s_setprio(1);                                            \
    _Pragma("unroll") for (int m = 0; m < 4; ++m)                             \
    _Pragma("unroll") for (int n = 0; n < 2; ++n)                             \
    _Pragma("unroll") for (int ks = 0; ks < 2; ++ks)                          \
        acc[m][n] = __builtin_amdgcn_mfma_f32_16x16x32_bf16(                  \
            a[m][ks], b0[n][ks], acc[m][n], 0, 0, 0);                         \
    __builtin_amdgcn_s_setprio(0);                                            \
    /* P0 tail: read b1(kt); stage B1(kt+1) */                                \
    _Pragma("unroll") for (int n = 0; n < 2; ++n) {                           \
        b1[n][0] = RDB(D, 1, n, 0); b1[n][1] = RDB(D, 1, n, 1); }             \
    if (S01) STAGE_B((kt) + 1, 1, (D) ^ 1);                                   \
    FENCE;                                                                    \
    /* -------- P1: quadrant (h=0,c=1) ----------------------------------- */ \
    __builtin_amdgcn_s_barrier();                                             \
    WAIT_LGKM;                                                                \
    __builtin_amdgcn_s_setprio(1);                                            \
    _Pragma("unroll") for (int m = 0; m < 4; ++m)                             \
    _Pragma("unroll") for (int n = 0; n < 2; ++n)                             \
    _Pragma("unroll") for (int ks = 0; ks < 2; ++ks)                          \
        acc[m][2 + n] = __builtin_amdgcn_mfma_f32_16x16x32_bf16(              \
            a[m][ks], b1[n][ks], acc[m][2 + n], 0, 0, 0);                     \
    __builtin_amdgcn_s_setprio(0);                                            \
    /* P1 tail: read a_h1(kt) (overwrites a[]); stage A1(kt+1) */             \
    _Pragma("unroll") for (int m = 0; m < 4; ++m) {                           \
        a[m][0] = RDA(D, 1, m, 0); a[m][1] = RDA(D, 1, m, 1); }               \
    if (S01) STAGE_A((kt) + 1, 1, (D) ^ 1);                                   \
    FENCE;                                                                    \
    /* -------- P2: quadrant (h=1,c=0) ----------------------------------- */ \
    __builtin_amdgcn_s_barrier();                                             \
    WAIT_LGKM;                                                                \
    __builtin_amdgcn_s_setprio(1);                                            \
    _Pragma("unroll") for (int m = 0; m < 4; ++m)                             \
    _Pragma("unroll") for (int n = 0; n < 2; ++n)                             \
    _Pragma("unroll") for (int ks = 0; ks < 2; ++ks)                          \
        acc[4 + m][n] = __builtin_amdgcn_mfma_f32_16x16x32_bf16(              \
            a[m][ks], b0[n][ks], acc[4 + m][n], 0, 0, 0);                     \
    __builtin_amdgcn_s_setprio(0);                                            \
    /* P2 tail: stage B0(kt+2) */                                             \
    if (S23) STAGE_B((kt) + 2, 0, D);                                         \
    FENCE;                                                                    \
    /* -------- P3: quadrant (h=1,c=1); operands already in regs --------- */ \
    __builtin_amdgcn_s_barrier();                                             \
    __builtin_amdgcn_s_setprio(1);                                            \
    _Pragma("unroll") for (int m = 0; m < 4; ++m)                             \
    _Pragma("unroll") for (int n = 0; n < 2; ++n)                             \
    _Pragma("unroll") for (int ks = 0; ks < 2; ++ks)                          \
        acc[4 + m][2 + n] = __builtin_amdgcn_mfma_f32_16x16x32_bf16(          \
            a[m][ks], b1[n][ks], acc[4 + m][2 + n], 0, 0, 0);                 \
    __builtin_amdgcn_s_setprio(0);                                            \
    /* P3 tail: stage A0(kt+2); counted vmcnt */                              \
    if (S23) STAGE_A((kt) + 2, 0, D);                                         \
    if ((VM) == 4) asm volatile("s_waitcnt vmcnt(4)" ::: "memory");           \
    else if ((VM) == 0) asm volatile("s_waitcnt vmcnt(0)" ::: "memory");      \
    FENCE;                                                                    \
    } while (0)

    // prologue: tile 0 fully + h0 of tile 1 (12 loads/thread);
    // vmcnt(4) completes all of tile 0, leaves B0(1),A0(1) pending.
    STAGE_B(0, 0, 0); STAGE_A(0, 0, 0);
    STAGE_B(0, 1, 0); STAGE_A(0, 1, 0);
    STAGE_B(1, 0, 1); STAGE_A(1, 0, 1);
    asm volatile("s_waitcnt vmcnt(4)" ::: "memory");

    for (int t = 0; t < (NT - 2) / 2; ++t) {   // k = 0 .. 61
        KTILE(2 * t, 0, 1, 1, 4);
        KTILE(2 * t + 1, 1, 1, 1, 4);
    }
    KTILE(NT - 2, 0, 1, 0, 0);                 // k = 62: stage h1(63), drain
    KTILE(NT - 1, 1, 0, 0, -1);                // k = 63: compute only

    // epilogue: C/D layout col=lane&15, row=(lane>>4)*4+r
    int row0 = by * BM + wr * 128 + (lane >> 4) * 4;
    int col0 = bx * BN + wc * 64 + lr;
#pragma unroll
    for (int c = 0; c < 2; ++c)
#pragma unroll
    for (int n = 0; n < 2; ++n) {
        int col = col0 + c * 32 + n * 16;
        float bv = bias[col];
#pragma unroll
        for (int h = 0; h < 2; ++h)
#pragma unroll
        for (int m = 0; m < 4; ++m)
#pragma unroll
        for (int r = 0; r < 4; ++r) {
            int row = row0 + h * 64 + m * 16 + r;
            C[(size_t)row * OUT_F + col] = acc[h * 4 + m][c * 2 + n][r] + bv;
        }
    }
#undef KTILE
#undef FENCE
#undef WAIT_LGKM
#undef RDA
#undef RDB
#undef STAGE_A
#undef STAGE_B
}

// ---------------------------------------------------------------------------
extern "C" void kernel_launch(void* const* d_in, const int* in_sizes, int n_in,
                              void* d_out, int out_size, void* d_ws, size_t ws_size,
                              hipStream_t stream) {
    const float* x      = (const float*)d_in[0];
    const int*   Wq     = (const int*)d_in[1];
    const int*   sq     = (const int*)d_in[2];
    const int*   zq     = (const int*)d_in[3];
    const float* ss     = (const float*)d_in[4];
    const float* zs     = (const float*)d_in[5];
    const float* sz     = (const float*)d_in[6];
    const float* zz     = (const float*)d_in[7];
    const float* bias   = (const float*)d_in[8];
    float* out = (float*)d_out;

    unsigned short* xb = (unsigned short*)d_ws;
    unsigned short* Wb = (unsigned short*)((char*)d_ws + (size_t)M_ROWS * IN_F * 2);

    // merged prep: dequant W + convert x (grid-stride, 2048 blocks)
    prep_kernel<<<2048, 256, 0, stream>>>(x, Wq, sq, zq, ss, zs, sz, zz, xb, Wb);
    // GEMM: (8192/256) * (4096/256) = 512 blocks, 512 threads
    gemm_bf16_kernel<<<512, 512, 0, stream>>>(xb, Wb, bias, out);
}

// Round 10
// 258.701 us; speedup vs baseline: 1.1192x; 1.0003x over previous
//
#include <hip/hip_runtime.h>
#include <hip/hip_bf16.h>

#define IN_F 4096
#define OUT_F 4096
#define M_ROWS 8192

#define BM 256
#define BN 256
#define BK 64
#define NT 64                  // IN_F / BK K-tiles

typedef __attribute__((ext_vector_type(8))) __bf16 bf16x8;
typedef __attribute__((ext_vector_type(4))) float f32x4;
typedef __attribute__((address_space(1))) const unsigned int GUI;
typedef __attribute__((address_space(3))) unsigned int LUI;

// ---------------------------------------------------------------------------
// Kernel 1 (merged prep): HQQ nested dequant Wq->bf16  AND  x fp32->bf16.
// Grid-stride over both independent domains; 2048 blocks x 256 threads.
// ---------------------------------------------------------------------------
__global__ __launch_bounds__(256) void prep_kernel(
    const float* __restrict__ x,
    const int* __restrict__ Wq, const int* __restrict__ sq, const int* __restrict__ zq,
    const float* __restrict__ ss, const float* __restrict__ zs,
    const float* __restrict__ sz, const float* __restrict__ zz,
    unsigned short* __restrict__ xb, unsigned short* __restrict__ Wb)
{
    const int nth = gridDim.x * blockDim.x;
    const int tid0 = blockIdx.x * blockDim.x + threadIdx.x;
    const float s_scale = ss[0], z_scale = zs[0], s_zero = sz[0], z_zero = zz[0];

    // ---- dequant W: 262144 groups x 8 jobs (8 elems/job, 32B in / 16B out)
    for (int tid = tid0; tid < (1 << 21); tid += nth) {
        int g = tid >> 3;
        int off = (tid & 7) << 3;
        float scale = ((float)sq[g] - z_scale) * s_scale;
        float zero  = ((float)zq[g] - z_zero) * s_zero;

        const int4* p = reinterpret_cast<const int4*>(Wq + ((size_t)g << 6) + off);
        int4 q0 = p[0], q1 = p[1];
        int qs[8] = {q0.x, q0.y, q0.z, q0.w, q1.x, q1.y, q1.z, q1.w};
        unsigned short w[8];
#pragma unroll
        for (int j = 0; j < 8; ++j) {
            __hip_bfloat16 b = __float2bfloat16(((float)qs[j] - zero) * scale);
            w[j] = *reinterpret_cast<unsigned short*>(&b);
        }
        *reinterpret_cast<int4*>(Wb + ((size_t)g << 6) + off) =
            *reinterpret_cast<int4*>(w);
    }

    // ---- convert x: 4,194,304 jobs (8 elems/job, 32B in / 16B out)
    for (size_t tid = tid0; tid < (size_t)(1 << 22); tid += nth) {
        size_t base = tid << 3;
        const float4* p = reinterpret_cast<const float4*>(x + base);
        float4 f0 = p[0], f1 = p[1];
        float fs[8] = {f0.x, f0.y, f0.z, f0.w, f1.x, f1.y, f1.z, f1.w};
        unsigned short w[8];
#pragma unroll
        for (int j = 0; j < 8; ++j) {
            __hip_bfloat16 b = __float2bfloat16(fs[j]);
            w[j] = *reinterpret_cast<unsigned short*>(&b);
        }
        *reinterpret_cast<int4*>(xb + base) = *reinterpret_cast<int4*>(w);
    }
}

// ---------------------------------------------------------------------------
// Kernel 2: 256x256 bf16 GEMM — round-4 verified structure; round-10 delta:
// (a) all barriers are asm("s_barrier":::"memory") (compiler fence both ways,
//     pins each phase's ds_reads inside its phase);
// (b) explicit lgkmcnt(0) drains REMOVED — compiler emits fine-grained
//     counted lgkmcnt between ds_read and dependent MFMA (m97 behavior),
//     so MFMA starts while later reads are still landing.
// WAR ledger unchanged: every read completes before its consuming MFMA,
// >=2 barriers before that region's overwrite. vmcnt(4) once per K-tile.
// ---------------------------------------------------------------------------
__global__ __launch_bounds__(512, 2) void gemm_bf16_kernel(
    const unsigned short* __restrict__ A,   // [M][K] bf16
    const unsigned short* __restrict__ B,   // [N][K] bf16
    const float* __restrict__ bias,
    float* __restrict__ C)
{
    // LDS: A bufs [0,64K), B bufs [64K,128K). Buf = 2 halves x 128 rows x 128B.
    // byte(row, slot) = row*128 + (slot^(row&7))*16.
    __shared__ __align__(16) char lds[131072];

    const int K = IN_F;

    // T1: bijective XCD swizzle (512 blocks, 8 XCDs)
    int bid = blockIdx.x;
    int swz = (bid & 7) * 64 + (bid >> 3);
    int bx = swz & 15;           // 16 N-tiles
    int by = swz >> 4;           // 32 M-tiles

    int tid = threadIdx.x;
    int lane = tid & 63;
    int wid = tid >> 6;
    int wr = wid >> 2;           // 0..1 (M)
    int wc = wid & 3;            // 0..3 (N)

    // staging addressing (linear LDS dest; pre-swizzled global source)
    int roff = tid >> 3;                                  // 0..63
    int soff = (((tid & 7) ^ ((tid >> 3) & 7)) << 3);     // src k-elem offset
    const unsigned short* srcA = A + (size_t)(by * BM + roff) * K + soff;
    const unsigned short* srcB = B + (size_t)(bx * BN + roff) * K + soff;

#define STAGE_A(kt, h, D2) do {                                               \
    __builtin_amdgcn_global_load_lds(                                         \
        (GUI*)(srcA + (size_t)((h)*128) * IN_F + (size_t)(kt) * BK),          \
        (LUI*)(lds + (D2)*32768 + (h)*16384 + wid*1024), 16, 0, 0);           \
    __builtin_amdgcn_global_load_lds(                                         \
        (GUI*)(srcA + (size_t)((h)*128 + 64) * IN_F + (size_t)(kt) * BK),     \
        (LUI*)(lds + (D2)*32768 + (h)*16384 + 8192 + wid*1024), 16, 0, 0);    \
    } while (0)
#define STAGE_B(kt, h, D2) do {                                               \
    __builtin_amdgcn_global_load_lds(                                         \
        (GUI*)(srcB + (size_t)((h)*128) * IN_F + (size_t)(kt) * BK),          \
        (LUI*)(lds + 65536 + (D2)*32768 + (h)*16384 + wid*1024), 16, 0, 0);   \
    __builtin_amdgcn_global_load_lds(                                         \
        (GUI*)(srcB + (size_t)((h)*128 + 64) * IN_F + (size_t)(kt) * BK),     \
        (LUI*)(lds + 65536 + (D2)*32768 + (h)*16384 + 8192 + wid*1024),       \
        16, 0, 0);                                                            \
    } while (0)

    // fragment read addressing (swizzled)
    int lr = lane & 15;
    int kq = lane >> 4;                       // 0..3
    int cslot = (kq ^ (lr & 3)) << 4;
    int offk0 = ((lr >> 2) & 1) << 6;
    int offk1 = 64 - offk0;
    int aRd = (wr * 128 + lr) * 128 + cslot;
    int bRd = (wc * 64 + lr) * 128 + cslot;

#define RDA(D2, h, m, ks) (*(const bf16x8*)(lds + (D2)*32768 + aRd +          \
        (h)*8192 + (m)*2048 + ((ks) ? offk1 : offk0)))
#define RDB(D2, c, n, ks) (*(const bf16x8*)(lds + 65536 + (D2)*32768 + bRd +  \
        (c)*4096 + (n)*2048 + ((ks) ? offk1 : offk0)))

    f32x4 acc[8][4] = {};
    bf16x8 a[4][2], b0[2][2], b1[2][2];

#define FENCE asm volatile("" ::: "memory")
// HW barrier + compiler memory fence (pins phase reads inside their phase)
#define BARRIER asm volatile("s_barrier" ::: "memory")

#define KTILE(kt, D, S01, S23, VM) do {                                       \
    /* -------- P0: quadrant (h=0,c=0); opening reads post-barrier ------- */ \
    BARRIER;                                                                  \
    _Pragma("unroll") for (int m = 0; m < 4; ++m) {                           \
        a[m][0] = RDA(D, 0, m, 0); a[m][1] = RDA(D, 0, m, 1); }               \
    _Pragma("unroll") for (int n = 0; n < 2; ++n) {                           \
        b0[n][0] = RDB(D, 0, n, 0); b0[n][1] = RDB(D, 0, n, 1); }             \
    __builtin_amdgcn_s_setprio(1);                                            \
    _Pragma("unroll") for (int m = 0; m < 4; ++m)                             \
    _Pragma("unroll") for (int n = 0; n < 2; ++n)                             \
    _Pragma("unroll") for (int ks = 0; ks < 2; ++ks)                          \
        acc[m][n] = __builtin_amdgcn_mfma_f32_16x16x32_bf16(                  \
            a[m][ks], b0[n][ks], acc[m][n], 0, 0, 0);                         \
    __builtin_amdgcn_s_setprio(0);                                            \
    /* P0 tail: read b1(kt); stage B1(kt+1) */                                \
    _Pragma("unroll") for (int n = 0; n < 2; ++n) {                           \
        b1[n][0] = RDB(D, 1, n, 0); b1[n][1] = RDB(D, 1, n, 1); }             \
    if (S01) STAGE_B((kt) + 1, 1, (D) ^ 1);                                   \
    FENCE;                                                                    \
    /* -------- P1: quadrant (h=0,c=1) ----------------------------------- */ \
    BARRIER;                                                                  \
    __builtin_amdgcn_s_setprio(1);                                            \
    _Pragma("unroll") for (int m = 0; m < 4; ++m)                             \
    _Pragma("unroll") for (int n = 0; n < 2; ++n)                             \
    _Pragma("unroll") for (int ks = 0; ks < 2; ++ks)                          \
        acc[m][2 + n] = __builtin_amdgcn_mfma_f32_16x16x32_bf16(              \
            a[m][ks], b1[n][ks], acc[m][2 + n], 0, 0, 0);                     \
    __builtin_amdgcn_s_setprio(0);                                            \
    /* P1 tail: read a_h1(kt) (overwrites a[]); stage A1(kt+1) */             \
    _Pragma("unroll") for (int m = 0; m < 4; ++m) {                           \
        a[m][0] = RDA(D, 1, m, 0); a[m][1] = RDA(D, 1, m, 1); }               \
    if (S01) STAGE_A((kt) + 1, 1, (D) ^ 1);                                   \
    FENCE;                                                                    \
    /* -------- P2: quadrant (h=1,c=0) ----------------------------------- */ \
    BARRIER;                                                                  \
    __builtin_amdgcn_s_setprio(1);                                            \
    _Pragma("unroll") for (int m = 0; m < 4; ++m)                             \
    _Pragma("unroll") for (int n = 0; n < 2; ++n)                             \
    _Pragma("unroll") for (int ks = 0; ks < 2; ++ks)                          \
        acc[4 + m][n] = __builtin_amdgcn_mfma_f32_16x16x32_bf16(              \
            a[m][ks], b0[n][ks], acc[4 + m][n], 0, 0, 0);                     \
    __builtin_amdgcn_s_setprio(0);                                            \
    /* P2 tail: stage B0(kt+2) */                                             \
    if (S23) STAGE_B((kt) + 2, 0, D);                                         \
    FENCE;                                                                    \
    /* -------- P3: quadrant (h=1,c=1); operands already in regs --------- */ \
    BARRIER;                                                                  \
    __builtin_amdgcn_s_setprio(1);                                            \
    _Pragma("unroll") for (int m = 0; m < 4; ++m)                             \
    _Pragma("unroll") for (int n = 0; n < 2; ++n)                             \
    _Pragma("unroll") for (int ks = 0; ks < 2; ++ks)                          \
        acc[4 + m][2 + n] = __builtin_amdgcn_mfma_f32_16x16x32_bf16(          \
            a[m][ks], b1[n][ks], acc[4 + m][2 + n], 0, 0, 0);                 \
    __builtin_amdgcn_s_setprio(0);                                            \
    /* P3 tail: stage A0(kt+2); counted vmcnt */                              \
    if (S23) STAGE_A((kt) + 2, 0, D);                                         \
    if ((VM) == 4) asm volatile("s_waitcnt vmcnt(4)" ::: "memory");           \
    else if ((VM) == 0) asm volatile("s_waitcnt vmcnt(0)" ::: "memory");      \
    FENCE;                                                                    \
    } while (0)

    // prologue: tile 0 fully + h0 of tile 1 (12 loads/thread);
    // vmcnt(4) completes all of tile 0, leaves B0(1),A0(1) pending.
    STAGE_B(0, 0, 0); STAGE_A(0, 0, 0);
    STAGE_B(0, 1, 0); STAGE_A(0, 1, 0);
    STAGE_B(1, 0, 1); STAGE_A(1, 0, 1);
    asm volatile("s_waitcnt vmcnt(4)" ::: "memory");

    for (int t = 0; t < (NT - 2) / 2; ++t) {   // k = 0 .. 61
        KTILE(2 * t, 0, 1, 1, 4);
        KTILE(2 * t + 1, 1, 1, 1, 4);
    }
    KTILE(NT - 2, 0, 1, 0, 0);                 // k = 62: stage h1(63), drain
    KTILE(NT - 1, 1, 0, 0, -1);                // k = 63: compute only

    // epilogue: C/D layout col=lane&15, row=(lane>>4)*4+r
    int row0 = by * BM + wr * 128 + (lane >> 4) * 4;
    int col0 = bx * BN + wc * 64 + lr;
#pragma unroll
    for (int c = 0; c < 2; ++c)
#pragma unroll
    for (int n = 0; n < 2; ++n) {
        int col = col0 + c * 32 + n * 16;
        float bv = bias[col];
#pragma unroll
        for (int h = 0; h < 2; ++h)
#pragma unroll
        for (int m = 0; m < 4; ++m)
#pragma unroll
        for (int r = 0; r < 4; ++r) {
            int row = row0 + h * 64 + m * 16 + r;
            C[(size_t)row * OUT_F + col] = acc[h * 4 + m][c * 2 + n][r] + bv;
        }
    }
#undef KTILE
#undef FENCE
#undef BARRIER
#undef RDA
#undef RDB
#undef STAGE_A
#undef STAGE_B
}

// ---------------------------------------------------------------------------
extern "C" void kernel_launch(void* const* d_in, const int* in_sizes, int n_in,
                              void* d_out, int out_size, void* d_ws, size_t ws_size,
                              hipStream_t stream) {
    const float* x      = (const float*)d_in[0];
    const int*   Wq     = (const int*)d_in[1];
    const int*   sq     = (const int*)d_in[2];
    const int*   zq     = (const int*)d_in[3];
    const float* ss     = (const float*)d_in[4];
    const float* zs     = (const float*)d_in[5];
    const float* sz     = (const float*)d_in[6];
    const float* zz     = (const float*)d_in[7];
    const float* bias   = (const float*)d_in[8];
    float* out = (float*)d_out;

    unsigned short* xb = (unsigned short*)d_ws;
    unsigned short* Wb = (unsigned short*)((char*)d_ws + (size_t)M_ROWS * IN_F * 2);

    // merged prep: dequant W + convert x (grid-stride, 2048 blocks)
    prep_kernel<<<2048, 256, 0, stream>>>(x, Wq, sq, zq, ss, zs, sz, zz, xb, Wb);
    // GEMM: (8192/256) * (4096/256) = 512 blocks, 512 threads
    gemm_bf16_kernel<<<512, 512, 0, stream>>>(xb, Wb, bias, out);
}

// Round 11
// 257.990 us; speedup vs baseline: 1.1223x; 1.0028x over previous
//
#include <hip/hip_runtime.h>
#include <hip/hip_bf16.h>

#define IN_F 4096
#define OUT_F 4096
#define M_ROWS 8192

#define BM 256
#define BN 256
#define BK 64
#define NT 64                  // IN_F / BK K-tiles

typedef __attribute__((ext_vector_type(8))) __bf16 bf16x8;
typedef __attribute__((ext_vector_type(4))) float f32x4;
typedef __attribute__((address_space(1))) const unsigned int GUI;
typedef __attribute__((address_space(3))) unsigned int LUI;

// ---------------------------------------------------------------------------
// Kernel 1 (merged prep): HQQ nested dequant Wq->bf16  AND  x fp32->bf16.
// ---------------------------------------------------------------------------
__global__ __launch_bounds__(256) void prep_kernel(
    const float* __restrict__ x,
    const int* __restrict__ Wq, const int* __restrict__ sq, const int* __restrict__ zq,
    const float* __restrict__ ss, const float* __restrict__ zs,
    const float* __restrict__ sz, const float* __restrict__ zz,
    unsigned short* __restrict__ xb, unsigned short* __restrict__ Wb)
{
    const int nth = gridDim.x * blockDim.x;
    const int tid0 = blockIdx.x * blockDim.x + threadIdx.x;
    const float s_scale = ss[0], z_scale = zs[0], s_zero = sz[0], z_zero = zz[0];

    for (int tid = tid0; tid < (1 << 21); tid += nth) {
        int g = tid >> 3;
        int off = (tid & 7) << 3;
        float scale = ((float)sq[g] - z_scale) * s_scale;
        float zero  = ((float)zq[g] - z_zero) * s_zero;

        const int4* p = reinterpret_cast<const int4*>(Wq + ((size_t)g << 6) + off);
        int4 q0 = p[0], q1 = p[1];
        int qs[8] = {q0.x, q0.y, q0.z, q0.w, q1.x, q1.y, q1.z, q1.w};
        unsigned short w[8];
#pragma unroll
        for (int j = 0; j < 8; ++j) {
            __hip_bfloat16 b = __float2bfloat16(((float)qs[j] - zero) * scale);
            w[j] = *reinterpret_cast<unsigned short*>(&b);
        }
        *reinterpret_cast<int4*>(Wb + ((size_t)g << 6) + off) =
            *reinterpret_cast<int4*>(w);
    }

    for (size_t tid = tid0; tid < (size_t)(1 << 22); tid += nth) {
        size_t base = tid << 3;
        const float4* p = reinterpret_cast<const float4*>(x + base);
        float4 f0 = p[0], f1 = p[1];
        float fs[8] = {f0.x, f0.y, f0.z, f0.w, f1.x, f1.y, f1.z, f1.w};
        unsigned short w[8];
#pragma unroll
        for (int j = 0; j < 8; ++j) {
            __hip_bfloat16 b = __float2bfloat16(fs[j]);
            w[j] = *reinterpret_cast<unsigned short*>(&b);
        }
        *reinterpret_cast<int4*>(xb + base) = *reinterpret_cast<int4*>(w);
    }
}

// ---------------------------------------------------------------------------
// Kernel 2: 256x256 bf16 GEMM — round-4 verified choreography, round-11
// delta: barriers at P0-top and P1-top ONLY (2 per K-tile, was 4).
// Ledger: (1) publication of k+1 = per-thread vmcnt(4) + P0-top barrier
// (unchanged). (2) read-before-overwrite for k+2 stages into buffer D:
//   b0/a_h0(k) reads complete before each wave's P0-MFMA -> before P1-top;
//   stages B0/A0(k+2) issue after P1-top  => >=1 barrier separation.
//   b1/a_h1(k) reads complete before MFMA#2/#3 -> before next P0-top;
//   their overwrites issue after it        => >=1 barrier separation.
// No read moves across any publication boundary (unlike the failed v2).
// All barriers are asm("s_barrier":::"memory") — compiler fence both ways.
// ---------------------------------------------------------------------------
__global__ __launch_bounds__(512, 2) void gemm_bf16_kernel(
    const unsigned short* __restrict__ A,   // [M][K] bf16
    const unsigned short* __restrict__ B,   // [N][K] bf16
    const float* __restrict__ bias,
    float* __restrict__ C)
{
    // LDS: A bufs [0,64K), B bufs [64K,128K). Buf = 2 halves x 128 rows x 128B.
    // byte(row, slot) = row*128 + (slot^(row&7))*16.
    __shared__ __align__(16) char lds[131072];

    const int K = IN_F;

    // T1: bijective XCD swizzle (512 blocks, 8 XCDs)
    int bid = blockIdx.x;
    int swz = (bid & 7) * 64 + (bid >> 3);
    int bx = swz & 15;           // 16 N-tiles
    int by = swz >> 4;           // 32 M-tiles

    int tid = threadIdx.x;
    int lane = tid & 63;
    int wid = tid >> 6;
    int wr = wid >> 2;           // 0..1 (M)
    int wc = wid & 3;            // 0..3 (N)

    // staging addressing (linear LDS dest; pre-swizzled global source)
    int roff = tid >> 3;                                  // 0..63
    int soff = (((tid & 7) ^ ((tid >> 3) & 7)) << 3);     // src k-elem offset
    const unsigned short* srcA = A + (size_t)(by * BM + roff) * K + soff;
    const unsigned short* srcB = B + (size_t)(bx * BN + roff) * K + soff;

#define STAGE_A(kt, h, D2) do {                                               \
    __builtin_amdgcn_global_load_lds(                                         \
        (GUI*)(srcA + (size_t)((h)*128) * IN_F + (size_t)(kt) * BK),          \
        (LUI*)(lds + (D2)*32768 + (h)*16384 + wid*1024), 16, 0, 0);           \
    __builtin_amdgcn_global_load_lds(                                         \
        (GUI*)(srcA + (size_t)((h)*128 + 64) * IN_F + (size_t)(kt) * BK),     \
        (LUI*)(lds + (D2)*32768 + (h)*16384 + 8192 + wid*1024), 16, 0, 0);    \
    } while (0)
#define STAGE_B(kt, h, D2) do {                                               \
    __builtin_amdgcn_global_load_lds(                                         \
        (GUI*)(srcB + (size_t)((h)*128) * IN_F + (size_t)(kt) * BK),          \
        (LUI*)(lds + 65536 + (D2)*32768 + (h)*16384 + wid*1024), 16, 0, 0);   \
    __builtin_amdgcn_global_load_lds(                                         \
        (GUI*)(srcB + (size_t)((h)*128 + 64) * IN_F + (size_t)(kt) * BK),     \
        (LUI*)(lds + 65536 + (D2)*32768 + (h)*16384 + 8192 + wid*1024),       \
        16, 0, 0);                                                            \
    } while (0)

    // fragment read addressing (swizzled)
    int lr = lane & 15;
    int kq = lane >> 4;                       // 0..3
    int cslot = (kq ^ (lr & 3)) << 4;
    int offk0 = ((lr >> 2) & 1) << 6;
    int offk1 = 64 - offk0;
    int aRd = (wr * 128 + lr) * 128 + cslot;
    int bRd = (wc * 64 + lr) * 128 + cslot;

#define RDA(D2, h, m, ks) (*(const bf16x8*)(lds + (D2)*32768 + aRd +          \
        (h)*8192 + (m)*2048 + ((ks) ? offk1 : offk0)))
#define RDB(D2, c, n, ks) (*(const bf16x8*)(lds + 65536 + (D2)*32768 + bRd +  \
        (c)*4096 + (n)*2048 + ((ks) ? offk1 : offk0)))

    f32x4 acc[8][4] = {};
    bf16x8 a[4][2], b0[2][2], b1[2][2];

#define FENCE asm volatile("" ::: "memory")
// HW barrier + compiler memory fence
#define BARRIER asm volatile("s_barrier" ::: "memory")

#define KTILE(kt, D, S01, S23, VM) do {                                       \
    /* ---- Phase A (barrier): quadrant (h=0,c=0) ------------------------ */ \
    BARRIER;                                                                  \
    _Pragma("unroll") for (int m = 0; m < 4; ++m) {                           \
        a[m][0] = RDA(D, 0, m, 0); a[m][1] = RDA(D, 0, m, 1); }               \
    _Pragma("unroll") for (int n = 0; n < 2; ++n) {                           \
        b0[n][0] = RDB(D, 0, n, 0); b0[n][1] = RDB(D, 0, n, 1); }             \
    __builtin_amdgcn_s_setprio(1);                                            \
    _Pragma("unroll") for (int m = 0; m < 4; ++m)                             \
    _Pragma("unroll") for (int n = 0; n < 2; ++n)                             \
    _Pragma("unroll") for (int ks = 0; ks < 2; ++ks)                          \
        acc[m][n] = __builtin_amdgcn_mfma_f32_16x16x32_bf16(                  \
            a[m][ks], b0[n][ks], acc[m][n], 0, 0, 0);                         \
    __builtin_amdgcn_s_setprio(0);                                            \
    /* tail: read b1(kt); stage B1(kt+1)->D^1 */                              \
    _Pragma("unroll") for (int n = 0; n < 2; ++n) {                           \
        b1[n][0] = RDB(D, 1, n, 0); b1[n][1] = RDB(D, 1, n, 1); }             \
    if (S01) STAGE_B((kt) + 1, 1, (D) ^ 1);                                   \
    FENCE;                                                                    \
    /* ---- Phase B (barrier): quadrants (0,1) then (1,0) then (1,1) ----- */ \
    BARRIER;                                                                  \
    __builtin_amdgcn_s_setprio(1);                                            \
    _Pragma("unroll") for (int m = 0; m < 4; ++m)                             \
    _Pragma("unroll") for (int n = 0; n < 2; ++n)                             \
    _Pragma("unroll") for (int ks = 0; ks < 2; ++ks)                          \
        acc[m][2 + n] = __builtin_amdgcn_mfma_f32_16x16x32_bf16(              \
            a[m][ks], b1[n][ks], acc[m][2 + n], 0, 0, 0);                     \
    __builtin_amdgcn_s_setprio(0);                                            \
    /* tail: read a_h1(kt) (overwrites a[]); stage A1(kt+1)->D^1 */           \
    _Pragma("unroll") for (int m = 0; m < 4; ++m) {                           \
        a[m][0] = RDA(D, 1, m, 0); a[m][1] = RDA(D, 1, m, 1); }               \
    if (S01) STAGE_A((kt) + 1, 1, (D) ^ 1);                                   \
    FENCE;                                                                    \
    /* (no barrier) quadrant (h=1,c=0) — a_h1 via compiler lgkm wait */       \
    __builtin_amdgcn_s_setprio(1);                                            \
    _Pragma("unroll") for (int m = 0; m < 4; ++m)                             \
    _Pragma("unroll") for (int n = 0; n < 2; ++n)                             \
    _Pragma("unroll") for (int ks = 0; ks < 2; ++ks)                          \
        acc[4 + m][n] = __builtin_amdgcn_mfma_f32_16x16x32_bf16(              \
            a[m][ks], b0[n][ks], acc[4 + m][n], 0, 0, 0);                     \
    __builtin_amdgcn_s_setprio(0);                                            \
    /* tail: stage B0(kt+2)->D (reads of B0(kt) done before P1-top) */        \
    if (S23) STAGE_B((kt) + 2, 0, D);                                         \
    FENCE;                                                                    \
    /* (no barrier) quadrant (h=1,c=1) — operands already in regs */          \
    __builtin_amdgcn_s_setprio(1);                                            \
    _Pragma("unroll") for (int m = 0; m < 4; ++m)                             \
    _Pragma("unroll") for (int n = 0; n < 2; ++n)                             \
    _Pragma("unroll") for (int ks = 0; ks < 2; ++ks)                          \
        acc[4 + m][2 + n] = __builtin_amdgcn_mfma_f32_16x16x32_bf16(          \
            a[m][ks], b1[n][ks], acc[4 + m][2 + n], 0, 0, 0);                 \
    __builtin_amdgcn_s_setprio(0);                                            \
    /* tail: stage A0(kt+2)->D; counted vmcnt (covers all of kt+1) */         \
    if (S23) STAGE_A((kt) + 2, 0, D);                                         \
    if ((VM) == 4) asm volatile("s_waitcnt vmcnt(4)" ::: "memory");           \
    else if ((VM) == 0) asm volatile("s_waitcnt vmcnt(0)" ::: "memory");      \
    FENCE;                                                                    \
    } while (0)

    // prologue: tile 0 fully + h0 of tile 1 (12 loads/thread);
    // vmcnt(4) completes all of tile 0, leaves B0(1),A0(1) pending.
    STAGE_B(0, 0, 0); STAGE_A(0, 0, 0);
    STAGE_B(0, 1, 0); STAGE_A(0, 1, 0);
    STAGE_B(1, 0, 1); STAGE_A(1, 0, 1);
    asm volatile("s_waitcnt vmcnt(4)" ::: "memory");

    for (int t = 0; t < (NT - 2) / 2; ++t) {   // k = 0 .. 61
        KTILE(2 * t, 0, 1, 1, 4);
        KTILE(2 * t + 1, 1, 1, 1, 4);
    }
    KTILE(NT - 2, 0, 1, 0, 0);                 // k = 62: stage h1(63), drain
    KTILE(NT - 1, 1, 0, 0, -1);                // k = 63: compute only

    // epilogue: C/D layout col=lane&15, row=(lane>>4)*4+r
    int row0 = by * BM + wr * 128 + (lane >> 4) * 4;
    int col0 = bx * BN + wc * 64 + lr;
#pragma unroll
    for (int c = 0; c < 2; ++c)
#pragma unroll
    for (int n = 0; n < 2; ++n) {
        int col = col0 + c * 32 + n * 16;
        float bv = bias[col];
#pragma unroll
        for (int h = 0; h < 2; ++h)
#pragma unroll
        for (int m = 0; m < 4; ++m)
#pragma unroll
        for (int r = 0; r < 4; ++r) {
            int row = row0 + h * 64 + m * 16 + r;
            C[(size_t)row * OUT_F + col] = acc[h * 4 + m][c * 2 + n][r] + bv;
        }
    }
#undef KTILE
#undef FENCE
#undef BARRIER
#undef RDA
#undef RDB
#undef STAGE_A
#undef STAGE_B
}

// ---------------------------------------------------------------------------
extern "C" void kernel_launch(void* const* d_in, const int* in_sizes, int n_in,
                              void* d_out, int out_size, void* d_ws, size_t ws_size,
                              hipStream_t stream) {
    const float* x      = (const float*)d_in[0];
    const int*   Wq     = (const int*)d_in[1];
    const int*   sq     = (const int*)d_in[2];
    const int*   zq     = (const int*)d_in[3];
    const float* ss     = (const float*)d_in[4];
    const float* zs     = (const float*)d_in[5];
    const float* sz     = (const float*)d_in[6];
    const float* zz     = (const float*)d_in[7];
    const float* bias   = (const float*)d_in[8];
    float* out = (float*)d_out;

    unsigned short* xb = (unsigned short*)d_ws;
    unsigned short* Wb = (unsigned short*)((char*)d_ws + (size_t)M_ROWS * IN_F * 2);

    // merged prep: dequant W + convert x (grid-stride, 2048 blocks)
    prep_kernel<<<2048, 256, 0, stream>>>(x, Wq, sq, zq, ss, zs, sz, zz, xb, Wb);
    // GEMM: (8192/256) * (4096/256) = 512 blocks, 512 threads
    gemm_bf16_kernel<<<512, 512, 0, stream>>>(xb, Wb, bias, out);
}

// Round 13
// 256.754 us; speedup vs baseline: 1.1277x; 1.0048x over previous
//
#include <hip/hip_runtime.h>
#include <hip/hip_bf16.h>

#define IN_F 4096
#define OUT_F 4096
#define M_ROWS 8192

#define BM 256
#define BN 256
#define BK 64
#define NT 64                  // IN_F / BK K-tiles

typedef __attribute__((ext_vector_type(8))) __bf16 bf16x8;
typedef __attribute__((ext_vector_type(4))) float f32x4;
typedef __attribute__((address_space(1))) const unsigned int GUI;
typedef __attribute__((address_space(3))) unsigned int LUI;

// ---------------------------------------------------------------------------
// Kernel 1 (merged prep): HQQ nested dequant Wq->bf16  AND  x fp32->bf16.
// ---------------------------------------------------------------------------
__global__ __launch_bounds__(256) void prep_kernel(
    const float* __restrict__ x,
    const int* __restrict__ Wq, const int* __restrict__ sq, const int* __restrict__ zq,
    const float* __restrict__ ss, const float* __restrict__ zs,
    const float* __restrict__ sz, const float* __restrict__ zz,
    unsigned short* __restrict__ xb, unsigned short* __restrict__ Wb)
{
    const int nth = gridDim.x * blockDim.x;
    const int tid0 = blockIdx.x * blockDim.x + threadIdx.x;
    const float s_scale = ss[0], z_scale = zs[0], s_zero = sz[0], z_zero = zz[0];

    for (int tid = tid0; tid < (1 << 21); tid += nth) {
        int g = tid >> 3;
        int off = (tid & 7) << 3;
        float scale = ((float)sq[g] - z_scale) * s_scale;
        float zero  = ((float)zq[g] - z_zero) * s_zero;

        const int4* p = reinterpret_cast<const int4*>(Wq + ((size_t)g << 6) + off);
        int4 q0 = p[0], q1 = p[1];
        int qs[8] = {q0.x, q0.y, q0.z, q0.w, q1.x, q1.y, q1.z, q1.w};
        unsigned short w[8];
#pragma unroll
        for (int j = 0; j < 8; ++j) {
            __hip_bfloat16 b = __float2bfloat16(((float)qs[j] - zero) * scale);
            w[j] = *reinterpret_cast<unsigned short*>(&b);
        }
        *reinterpret_cast<int4*>(Wb + ((size_t)g << 6) + off) =
            *reinterpret_cast<int4*>(w);
    }

    for (size_t tid = tid0; tid < (size_t)(1 << 22); tid += nth) {
        size_t base = tid << 3;
        const float4* p = reinterpret_cast<const float4*>(x + base);
        float4 f0 = p[0], f1 = p[1];
        float fs[8] = {f0.x, f0.y, f0.z, f0.w, f1.x, f1.y, f1.z, f1.w};
        unsigned short w[8];
#pragma unroll
        for (int j = 0; j < 8; ++j) {
            __hip_bfloat16 b = __float2bfloat16(fs[j]);
            w[j] = *reinterpret_cast<unsigned short*>(&b);
        }
        *reinterpret_cast<int4*>(xb + base) = *reinterpret_cast<int4*>(w);
    }
}

// ---------------------------------------------------------------------------
// Kernel 2: 256x256 bf16 GEMM — round-11 verified configuration (final).
//   C[M][N] = A[M][K] * B[N][K]^T + bias
// 8 waves (2M x 4N), wave tile 128x64, BK=64, dbuf LDS 128 KiB, 16x16x32
// MFMA, XOR-swizzled LDS (0 bank conflicts), XCD-aware block swizzle.
// 2 barriers per K-tile (P0-top publication, P1-top WAR separator), rotated
// tails hide ds_reads/stages under the SIMD-partner's MFMA window,
// vmcnt(4) counted once per K-tile (never 0 in the main loop).
// Measured: ~216 us GEMM (1.27 PF, 51% dense), MfmaUtil ~59%.
// ---------------------------------------------------------------------------
__global__ __launch_bounds__(512, 2) void gemm_bf16_kernel(
    const unsigned short* __restrict__ A,   // [M][K] bf16
    const unsigned short* __restrict__ B,   // [N][K] bf16
    const float* __restrict__ bias,
    float* __restrict__ C)
{
    // LDS: A bufs [0,64K), B bufs [64K,128K). Buf = 2 halves x 128 rows x 128B.
    // byte(row, slot) = row*128 + (slot^(row&7))*16.
    __shared__ __align__(16) char lds[131072];

    const int K = IN_F;

    // T1: bijective XCD swizzle (512 blocks, 8 XCDs)
    int bid = blockIdx.x;
    int swz = (bid & 7) * 64 + (bid >> 3);
    int bx = swz & 15;           // 16 N-tiles
    int by = swz >> 4;           // 32 M-tiles

    int tid = threadIdx.x;
    int lane = tid & 63;
    int wid = tid >> 6;
    int wr = wid >> 2;           // 0..1 (M)
    int wc = wid & 3;            // 0..3 (N)

    // staging addressing (linear LDS dest; pre-swizzled global source)
    int roff = tid >> 3;                                  // 0..63
    int soff = (((tid & 7) ^ ((tid >> 3) & 7)) << 3);     // src k-elem offset
    const unsigned short* srcA = A + (size_t)(by * BM + roff) * K + soff;
    const unsigned short* srcB = B + (size_t)(bx * BN + roff) * K + soff;

#define STAGE_A(kt, h, D2) do {                                               \
    __builtin_amdgcn_global_load_lds(                                         \
        (GUI*)(srcA + (size_t)((h)*128) * IN_F + (size_t)(kt) * BK),          \
        (LUI*)(lds + (D2)*32768 + (h)*16384 + wid*1024), 16, 0, 0);           \
    __builtin_amdgcn_global_load_lds(                                         \
        (GUI*)(srcA + (size_t)((h)*128 + 64) * IN_F + (size_t)(kt) * BK),     \
        (LUI*)(lds + (D2)*32768 + (h)*16384 + 8192 + wid*1024), 16, 0, 0);    \
    } while (0)
#define STAGE_B(kt, h, D2) do {                                               \
    __builtin_amdgcn_global_load_lds(                                         \
        (GUI*)(srcB + (size_t)((h)*128) * IN_F + (size_t)(kt) * BK),          \
        (LUI*)(lds + 65536 + (D2)*32768 + (h)*16384 + wid*1024), 16, 0, 0);   \
    __builtin_amdgcn_global_load_lds(                                         \
        (GUI*)(srcB + (size_t)((h)*128 + 64) * IN_F + (size_t)(kt) * BK),     \
        (LUI*)(lds + 65536 + (D2)*32768 + (h)*16384 + 8192 + wid*1024),       \
        16, 0, 0);                                                            \
    } while (0)

    // fragment read addressing (swizzled)
    int lr = lane & 15;
    int kq = lane >> 4;                       // 0..3
    int cslot = (kq ^ (lr & 3)) << 4;
    int offk0 = ((lr >> 2) & 1) << 6;
    int offk1 = 64 - offk0;
    int aRd = (wr * 128 + lr) * 128 + cslot;
    int bRd = (wc * 64 + lr) * 128 + cslot;

#define RDA(D2, h, m, ks) (*(const bf16x8*)(lds + (D2)*32768 + aRd +          \
        (h)*8192 + (m)*2048 + ((ks) ? offk1 : offk0)))
#define RDB(D2, c, n, ks) (*(const bf16x8*)(lds + 65536 + (D2)*32768 + bRd +  \
        (c)*4096 + (n)*2048 + ((ks) ? offk1 : offk0)))

    f32x4 acc[8][4] = {};
    bf16x8 a[4][2], b0[2][2], b1[2][2];

#define FENCE asm volatile("" ::: "memory")
// HW barrier + compiler memory fence
#define BARRIER asm volatile("s_barrier" ::: "memory")

#define KTILE(kt, D, S01, S23, VM) do {                                       \
    /* ---- Phase A (barrier): quadrant (h=0,c=0) ------------------------ */ \
    BARRIER;                                                                  \
    _Pragma("unroll") for (int m = 0; m < 4; ++m) {                           \
        a[m][0] = RDA(D, 0, m, 0); a[m][1] = RDA(D, 0, m, 1); }               \
    _Pragma("unroll") for (int n = 0; n < 2; ++n) {                           \
        b0[n][0] = RDB(D, 0, n, 0); b0[n][1] = RDB(D, 0, n, 1); }             \
    __builtin_amdgcn_s_setprio(1);                                            \
    _Pragma("unroll") for (int m = 0; m < 4; ++m)                             \
    _Pragma("unroll") for (int n = 0; n < 2; ++n)                             \
    _Pragma("unroll") for (int ks = 0; ks < 2; ++ks)                          \
        acc[m][n] = __builtin_amdgcn_mfma_f32_16x16x32_bf16(                  \
            a[m][ks], b0[n][ks], acc[m][n], 0, 0, 0);                         \
    __builtin_amdgcn_s_setprio(0);                                            \
    /* tail: read b1(kt); stage B1(kt+1)->D^1 */                              \
    _Pragma("unroll") for (int n = 0; n < 2; ++n) {                           \
        b1[n][0] = RDB(D, 1, n, 0); b1[n][1] = RDB(D, 1, n, 1); }             \
    if (S01) STAGE_B((kt) + 1, 1, (D) ^ 1);                                   \
    FENCE;                                                                    \
    /* ---- Phase B (barrier): quadrants (0,1) then (1,0) then (1,1) ----- */ \
    BARRIER;                                                                  \
    __builtin_amdgcn_s_setprio(1);                                            \
    _Pragma("unroll") for (int m = 0; m < 4; ++m)                             \
    _Pragma("unroll") for (int n = 0; n < 2; ++n)                             \
    _Pragma("unroll") for (int ks = 0; ks < 2; ++ks)                          \
        acc[m][2 + n] = __builtin_amdgcn_mfma_f32_16x16x32_bf16(              \
            a[m][ks], b1[n][ks], acc[m][2 + n], 0, 0, 0);                     \
    __builtin_amdgcn_s_setprio(0);                                            \
    /* tail: read a_h1(kt) (overwrites a[]); stage A1(kt+1)->D^1 */           \
    _Pragma("unroll") for (int m = 0; m < 4; ++m) {                           \
        a[m][0] = RDA(D, 1, m, 0); a[m][1] = RDA(D, 1, m, 1); }               \
    if (S01) STAGE_A((kt) + 1, 1, (D) ^ 1);                                   \
    FENCE;                                                                    \
    /* (no barrier) quadrant (h=1,c=0) — a_h1 via compiler lgkm wait */       \
    __builtin_amdgcn_s_setprio(1);                                            \
    _Pragma("unroll") for (int m = 0; m < 4; ++m)                             \
    _Pragma("unroll") for (int n = 0; n < 2; ++n)                             \
    _Pragma("unroll") for (int ks = 0; ks < 2; ++ks)                          \
        acc[4 + m][n] = __builtin_amdgcn_mfma_f32_16x16x32_bf16(              \
            a[m][ks], b0[n][ks], acc[4 + m][n], 0, 0, 0);                     \
    __builtin_amdgcn_s_setprio(0);                                            \
    /* tail: stage B0(kt+2)->D (reads of B0(kt) done before P1-top) */        \
    if (S23) STAGE_B((kt) + 2, 0, D);                                         \
    FENCE;                                                                    \
    /* (no barrier) quadrant (h=1,c=1) — operands already in regs */          \
    __builtin_amdgcn_s_setprio(1);                                            \
    _Pragma("unroll") for (int m = 0; m < 4; ++m)                             \
    _Pragma("unroll") for (int n = 0; n < 2; ++n)                             \
    _Pragma("unroll") for (int ks = 0; ks < 2; ++ks)                          \
        acc[4 + m][2 + n] = __builtin_amdgcn_mfma_f32_16x16x32_bf16(          \
            a[m][ks], b1[n][ks], acc[4 + m][2 + n], 0, 0, 0);                 \
    __builtin_amdgcn_s_setprio(0);                                            \
    /* tail: stage A0(kt+2)->D; counted vmcnt (covers all of kt+1) */         \
    if (S23) STAGE_A((kt) + 2, 0, D);                                         \
    if ((VM) == 4) asm volatile("s_waitcnt vmcnt(4)" ::: "memory");           \
    else if ((VM) == 0) asm volatile("s_waitcnt vmcnt(0)" ::: "memory");      \
    FENCE;                                                                    \
    } while (0)

    // prologue: tile 0 fully + h0 of tile 1 (12 loads/thread);
    // vmcnt(4) completes all of tile 0, leaves B0(1),A0(1) pending.
    STAGE_B(0, 0, 0); STAGE_A(0, 0, 0);
    STAGE_B(0, 1, 0); STAGE_A(0, 1, 0);
    STAGE_B(1, 0, 1); STAGE_A(1, 0, 1);
    asm volatile("s_waitcnt vmcnt(4)" ::: "memory");

    for (int t = 0; t < (NT - 2) / 2; ++t) {   // k = 0 .. 61
        KTILE(2 * t, 0, 1, 1, 4);
        KTILE(2 * t + 1, 1, 1, 1, 4);
    }
    KTILE(NT - 2, 0, 1, 0, 0);                 // k = 62: stage h1(63), drain
    KTILE(NT - 1, 1, 0, 0, -1);                // k = 63: compute only

    // epilogue: C/D layout col=lane&15, row=(lane>>4)*4+r
    int row0 = by * BM + wr * 128 + (lane >> 4) * 4;
    int col0 = bx * BN + wc * 64 + lr;
#pragma unroll
    for (int c = 0; c < 2; ++c)
#pragma unroll
    for (int n = 0; n < 2; ++n) {
        int col = col0 + c * 32 + n * 16;
        float bv = bias[col];
#pragma unroll
        for (int h = 0; h < 2; ++h)
#pragma unroll
        for (int m = 0; m < 4; ++m)
#pragma unroll
        for (int r = 0; r < 4; ++r) {
            int row = row0 + h * 64 + m * 16 + r;
            C[(size_t)row * OUT_F + col] = acc[h * 4 + m][c * 2 + n][r] + bv;
        }
    }
#undef KTILE
#undef FENCE
#undef BARRIER
#undef RDA
#undef RDB
#undef STAGE_A
#undef STAGE_B
}

// ---------------------------------------------------------------------------
extern "C" void kernel_launch(void* const* d_in, const int* in_sizes, int n_in,
                              void* d_out, int out_size, void* d_ws, size_t ws_size,
                              hipStream_t stream) {
    const float* x      = (const float*)d_in[0];
    const int*   Wq     = (const int*)d_in[1];
    const int*   sq     = (const int*)d_in[2];
    const int*   zq     = (const int*)d_in[3];
    const float* ss     = (const float*)d_in[4];
    const float* zs     = (const float*)d_in[5];
    const float* sz     = (const float*)d_in[6];
    const float* zz     = (const float*)d_in[7];
    const float* bias   = (const float*)d_in[8];
    float* out = (float*)d_out;

    unsigned short* xb = (unsigned short*)d_ws;
    unsigned short* Wb = (unsigned short*)((char*)d_ws + (size_t)M_ROWS * IN_F * 2);

    // merged prep: dequant W + convert x (grid-stride, 2048 blocks)
    prep_kernel<<<2048, 256, 0, stream>>>(x, Wq, sq, zq, ss, zs, sz, zz, xb, Wb);
    // GEMM: (8192/256) * (4096/256) = 512 blocks, 512 threads
    gemm_bf16_kernel<<<512, 512, 0, stream>>>(xb, Wb, bias, out);
}